// Round 12
// baseline (896.113 us; speedup 1.0000x reference)
//
#include <hip/hip_runtime.h>

#define NUM_USER 100000
#define NUM_ITEM 50000
#define HID 64
#define NNZ 1600000
#define NEDGE (2 * NNZ)          // 3,200,000
#define REGC 1e-4f
#define BATCH 16384
#define NROWS (NUM_USER + NUM_ITEM)   // 150,000
#define NELEM (NROWS * HID)           // 9,600,000

#define NB 1024                  // edge-slice blocks
#define SLICE (NEDGE / NB)       // 3125 exact
#define RPP 512                  // rows per coarse partition (row >> 9)
#define NPART ((NROWS + RPP - 1) / RPP)  // 293

// ---------------------------------------------------------------------------
// passA: per-block LDS histogram of coarse partition ids -> cmat[p][b]
// ---------------------------------------------------------------------------
__global__ __launch_bounds__(256) void passA_kernel(const int* __restrict__ erow,
                                                    int* __restrict__ cmat) {
  __shared__ int h[NPART];
  const int b = blockIdx.x, t = threadIdx.x;
  if (t < NPART) h[t] = 0;
  if (t + 256 < NPART) h[t + 256] = 0;
  __syncthreads();
  const int s = b * SLICE, e = s + SLICE;
  for (int i = s + t; i < e; i += 256) atomicAdd(&h[erow[i] >> 9], 1);
  __syncthreads();
  if (t < NPART) cmat[t * NB + b] = h[t];
  if (t + 256 < NPART) cmat[(t + 256) * NB + b] = h[t + 256];
}

// ---------------------------------------------------------------------------
// scan_bp: per-partition exclusive scan over blocks, in place; totals out.
// ---------------------------------------------------------------------------
__global__ __launch_bounds__(64) void scan_bp_kernel(int* __restrict__ cmat,
                                                     int* __restrict__ totals) {
  const int p = blockIdx.x;
  const int lane = threadIdx.x;
  int* col = cmat + (size_t)p * NB;
  int carry = 0;
  for (int base = 0; base < NB; base += 64) {
    const int v = col[base + lane];
    int incl = v;
    for (int off = 1; off < 64; off <<= 1) {
      const int tt = __shfl_up(incl, off);
      if (lane >= off) incl += tt;
    }
    col[base + lane] = carry + incl - v;  // exclusive within partition
    carry += __shfl(incl, 63);
  }
  if (lane == 0) totals[p] = carry;
}

// ---------------------------------------------------------------------------
// scan_base: exclusive scan of partition totals -> pbase; misc zeroing
// ---------------------------------------------------------------------------
__global__ __launch_bounds__(512) void scan_base_kernel(
    const int* __restrict__ totals, int* __restrict__ pbase,
    float* __restrict__ scal, int* __restrict__ rowp) {
  __shared__ int sA[512], sB[512];
  const int t = threadIdx.x;
  const int v = (t < NPART) ? totals[t] : 0;
  sA[t] = v;
  __syncthreads();
  int* in = sA;
  int* out = sB;
  for (int off = 1; off < 512; off <<= 1) {
    out[t] = in[t] + ((t >= off) ? in[t - off] : 0);
    __syncthreads();
    int* tmp = in; in = out; out = tmp;
  }
  if (t < NPART) pbase[t] = in[t] - v;
  if (t == 0) {
    pbase[NPART] = NEDGE;
    rowp[NROWS] = NEDGE;
    scal[0] = 0.f;
    scal[1] = 0.f;
  }
}

// ---------------------------------------------------------------------------
// passC: scatter edges into partition buckets; no global atomics.
// bucket word: (row & 511) << 18 | col   (col < 150000 < 2^18)
// ---------------------------------------------------------------------------
__global__ __launch_bounds__(256) void passC_kernel(
    const int* __restrict__ erow, const int* __restrict__ ecol,
    const int* __restrict__ cmat, const int* __restrict__ pbase,
    unsigned int* __restrict__ bucket) {
  __shared__ int cur[NPART];
  const int b = blockIdx.x, t = threadIdx.x;
  if (t < NPART) cur[t] = pbase[t] + cmat[t * NB + b];
  if (t + 256 < NPART) cur[t + 256] = pbase[t + 256] + cmat[(t + 256) * NB + b];
  __syncthreads();
  const int s = b * SLICE, e = s + SLICE;
  for (int i = s + t; i < e; i += 256) {
    const int r = erow[i];
    const int c = ecol[i];
    const int pos = atomicAdd(&cur[r >> 9], 1);
    bucket[pos] = ((unsigned int)(r & (RPP - 1)) << 18) | (unsigned int)c;
  }
}

// ---------------------------------------------------------------------------
// fine: one block per partition -> rowp/dinv/dinv2/rsq + final CSR ccol.
// ---------------------------------------------------------------------------
__global__ __launch_bounds__(256) void fine_kernel(
    const unsigned int* __restrict__ bucket, const int* __restrict__ pbase,
    int* __restrict__ ccol, int* __restrict__ rowp, float* __restrict__ dinv,
    float* __restrict__ dinv2, float* __restrict__ rsq) {
  __shared__ int cnt[RPP], sA[RPP], sB[RPP];
  const int p = blockIdx.x, t = threadIdx.x;
  const int start = pbase[p], end = pbase[p + 1];
  cnt[t] = 0;
  cnt[t + 256] = 0;
  __syncthreads();
  for (int i = start + t; i < end; i += 256) atomicAdd(&cnt[bucket[i] >> 18], 1);
  __syncthreads();
  sA[t] = cnt[t];
  sA[t + 256] = cnt[t + 256];
  __syncthreads();
  int* in = sA;
  int* out = sB;
  for (int off = 1; off < RPP; off <<= 1) {
    out[t] = in[t] + ((t >= off) ? in[t - off] : 0);
    const int t2 = t + 256;
    out[t2] = in[t2] + ((t2 >= off) ? in[t2 - off] : 0);
    __syncthreads();
    int* tmp = in; in = out; out = tmp;
  }
  // in[] = inclusive scan of cnt
  for (int r = t; r < RPP; r += 256) {
    const int row = p * RPP + r;
    if (row < NROWS) {
      const int deg = cnt[r];
      rowp[row] = start + in[r] - deg;
      dinv[row] = (deg > 0) ? (1.0f / sqrtf((float)deg)) : 0.f;
      dinv2[row] = (deg > 0) ? (1.0f / (float)deg) : 0.f;
      rsq[row] = (deg > 0) ? sqrtf((float)deg) : 0.f;
    }
  }
  out[t] = 0;
  out[t + 256] = 0;
  __syncthreads();
  for (int i = start + t; i < end; i += 256) {
    const unsigned int w = bucket[i];
    const int rl = w >> 18;
    const int posl = atomicAdd(&out[rl], 1);
    ccol[start + in[rl] - cnt[rl] + posl] = (int)(w & 0x3FFFFu);
  }
}

// ---------------------------------------------------------------------------
// init: Z0 = dinv ⊙ concat(uemb, iemb)
// ---------------------------------------------------------------------------
__global__ __launch_bounds__(256) void init_kernel(const float* __restrict__ uemb,
                                                   const float* __restrict__ iemb,
                                                   const float* __restrict__ dinv,
                                                   float* __restrict__ A) {
  const int tid = blockIdx.x * blockDim.x + threadIdx.x;
  const int stride = gridDim.x * blockDim.x;
  const int n4 = NELEM / 4;
  const int u4n = NUM_USER * HID / 4;
  const float4* __restrict__ u4 = (const float4*)uemb;
  const float4* __restrict__ i4 = (const float4*)iemb;
  float4* __restrict__ A4 = (float4*)A;
  for (int k = tid; k < n4; k += stride) {
    float4 v = (k < u4n) ? u4[k] : i4[k - u4n];
    const float dv = dinv[k >> 4];   // 16 float4 per row
    v.x *= dv; v.y *= dv; v.z *= dv; v.w *= dv;
    A4[k] = v;
  }
}

// ---------------------------------------------------------------------------
// shared gather helper: sum_{c in nbr(row)} z[c*64+lane]
// ---------------------------------------------------------------------------
__device__ __forceinline__ float row_gather_sum(
    const int* __restrict__ rowp, const int* __restrict__ ccol,
    const float* __restrict__ z, int row, int lane) {
  const int start = rowp[row];
  const int end = rowp[row + 1];
  float acc = 0.f;
  for (int base = start; base < end; base += 64) {
    const int idx = base + lane;
    const int cl = (idx < end) ? (ccol[idx] << 6) : 0;
    const int n = min(64, end - base);
    int k = 0;
    for (; k + 8 <= n; k += 8) {
      const int c0 = __shfl(cl, k + 0), c1 = __shfl(cl, k + 1);
      const int c2 = __shfl(cl, k + 2), c3 = __shfl(cl, k + 3);
      const int c4 = __shfl(cl, k + 4), c5 = __shfl(cl, k + 5);
      const int c6 = __shfl(cl, k + 6), c7 = __shfl(cl, k + 7);
      const float v0 = z[c0 + lane], v1 = z[c1 + lane];
      const float v2 = z[c2 + lane], v3 = z[c3 + lane];
      const float v4 = z[c4 + lane], v5 = z[c5 + lane];
      const float v6 = z[c6 + lane], v7 = z[c7 + lane];
      acc += v0; acc += v1; acc += v2; acc += v3;
      acc += v4; acc += v5; acc += v6; acc += v7;
    }
    for (; k < n; ++k) {
      const int c = __shfl(cl, k);
      acc += z[c + lane];
    }
  }
  return acc;
}

// ---------------------------------------------------------------------------
// spmm (pull, CSR): Z_out[r] = dinv2[r] * sum_{c in nbr(r)} Z_in[c]
// one wave per row, lane = hidden dim.
// ---------------------------------------------------------------------------
__global__ __launch_bounds__(256) void spmm_kernel(
    const int* __restrict__ rowp, const int* __restrict__ ccol,
    const float* __restrict__ dinv2, const float* __restrict__ zin,
    float* __restrict__ zout) {
  const int lane = threadIdx.x & 63;
  const int row = (blockIdx.x * blockDim.x + threadIdx.x) >> 6;
  if (row >= NROWS) return;
  const float yv = row_gather_sum(rowp, ccol, zin, row, lane);
  zout[(row << 6) + lane] = yv * dinv2[row];
}

// ---------------------------------------------------------------------------
// gather3: layer-3 ONLY at sampled rows. One wave per (sample,slot):
// slots [0,B) = u rows, [B,2B) = i rows, [2B,3B) = j rows.
// E[s] = dinv[row] * sum_{c in nbr(row)} Z2[c]   (== X3[row], since
// X3 = rsq*Z3 = rsq*dinv2*sum = dinv*sum). 49152 waves -> full TLP.
// ---------------------------------------------------------------------------
__global__ __launch_bounds__(256) void gather3_kernel(
    const int* __restrict__ u, const int* __restrict__ ii,
    const int* __restrict__ jj, const int* __restrict__ rowp,
    const int* __restrict__ ccol, const float* __restrict__ dinv,
    const float* __restrict__ z2, float* __restrict__ E) {
  const int s = (blockIdx.x * blockDim.x + threadIdx.x) >> 6;
  const int lane = threadIdx.x & 63;
  if (s >= 3 * BATCH) return;
  int row;
  if (s < BATCH) row = u[s];
  else if (s < 2 * BATCH) row = NUM_USER + ii[s - BATCH];
  else row = NUM_USER + jj[s - 2 * BATCH];
  const float acc = row_gather_sum(rowp, ccol, z2, row, lane);
  E[(s << 6) + lane] = acc * dinv[row];
}

// ---------------------------------------------------------------------------
// loss: one wave per sample, DIRECT loads only (all independent).
// e = 0.25*( emb0[row] + (Z1+Z2)[row]*rsq[row] + E[slot] )
// ---------------------------------------------------------------------------
__global__ __launch_bounds__(256) void loss_kernel(
    const int* __restrict__ u, const int* __restrict__ ii,
    const int* __restrict__ jj, const float* __restrict__ uemb,
    const float* __restrict__ iemb, const float* __restrict__ Z1,
    const float* __restrict__ Z2, const float* __restrict__ E,
    const float* __restrict__ rsq, float* __restrict__ scal) {
  const int b = (blockIdx.x * blockDim.x + threadIdx.x) >> 6;
  const int lane = threadIdx.x & 63;
  if (b >= BATCH) return;

  const int ur = u[b];
  const int il = ii[b];
  const int jl = jj[b];
  const int pr = NUM_USER + il;
  const int nr = NUM_USER + jl;
  const int uo = (ur << 6) + lane;
  const int po = (pr << 6) + lane;
  const int no = (nr << 6) + lane;

  const float e0u = uemb[uo];
  const float e0p = iemb[(il << 6) + lane];
  const float e0n = iemb[(jl << 6) + lane];
  const float z1u = Z1[uo], z2u = Z2[uo];
  const float z1p = Z1[po], z2p = Z2[po];
  const float z1n = Z1[no], z2n = Z2[no];
  const float Eu = E[(b << 6) + lane];
  const float Ep = E[((BATCH + b) << 6) + lane];
  const float En = E[((2 * BATCH + b) << 6) + lane];
  const float rqu = rsq[ur], rqp = rsq[pr], rqn = rsq[nr];

  const float ue = 0.25f * (e0u + (z1u + z2u) * rqu + Eu);
  const float pe = 0.25f * (e0p + (z1p + z2p) * rqp + Ep);
  const float ne = 0.25f * (e0n + (z1n + z2n) * rqn + En);

  float s1 = ue * pe;
  float s2 = ue * ne;
  float s3 = ue * ue + pe * pe + ne * ne;
  for (int off = 32; off; off >>= 1) {
    s1 += __shfl_down(s1, off);
    s2 += __shfl_down(s2, off);
    s3 += __shfl_down(s3, off);
  }
  if (lane == 0) {
    const float z = s1 - s2;
    const float ls = fminf(z, 0.f) - log1pf(expf(-fabsf(z)));
    atomicAdd(&scal[0], ls);
    atomicAdd(&scal[1], s3);
  }
}

__global__ void finalize_kernel(const float* __restrict__ scal,
                                float* __restrict__ out) {
  const float bpr = -scal[0] / (float)BATCH;
  const float l2 = scal[1] * 0.5f / (float)BATCH;
  out[0] = bpr + REGC * l2;
}

// ---------------------------------------------------------------------------
extern "C" void kernel_launch(void* const* d_in, const int* in_sizes, int n_in,
                              void* d_out, int out_size, void* d_ws,
                              size_t ws_size, hipStream_t stream) {
  const int* u = (const int*)d_in[0];
  const int* ii = (const int*)d_in[1];
  const int* jj = (const int*)d_in[2];
  const int* erow = (const int*)d_in[3];
  const int* ecol = (const int*)d_in[4];
  // d_in[5] (edge_val) unused: weights recomputed from degrees.
  const float* uemb = (const float*)d_in[6];
  const float* iemb = (const float*)d_in[7];
  float* out = (float*)d_out;

  float* ws = (float*)d_ws;
  float* A = ws;                       // Z0 -> Z2; hosts bucket+cmat first
  float* B = A + (size_t)NELEM;        // Z1
  int* ccol = (int*)(B + (size_t)NELEM);
  int* rowp = ccol + (size_t)NEDGE;    // NROWS+1
  float* dinv = (float*)(rowp + NROWS + 1);
  float* dinv2 = dinv + NROWS;
  float* rsq = dinv2 + NROWS;
  int* totals = (int*)(rsq + NROWS);   // NPART
  int* pbase = totals + NPART;         // NPART+1
  float* scal = (float*)(pbase + NPART + 1);
  float* E = scal + 2;                 // 3*BATCH*64 floats = 12.6 MB

  // aliased inside A (dead before init writes Z0):
  unsigned int* bucket = (unsigned int*)A;          // NEDGE u32 = 12.8 MB
  int* cmat = (int*)A + (size_t)NEDGE;              // NPART*NB ints = 1.2 MB

  passA_kernel<<<NB, 256, 0, stream>>>(erow, cmat);
  scan_bp_kernel<<<NPART, 64, 0, stream>>>(cmat, totals);
  scan_base_kernel<<<1, 512, 0, stream>>>(totals, pbase, scal, rowp);
  passC_kernel<<<NB, 256, 0, stream>>>(erow, ecol, cmat, pbase, bucket);
  fine_kernel<<<NPART, 256, 0, stream>>>(bucket, pbase, ccol, rowp, dinv,
                                         dinv2, rsq);

  init_kernel<<<2048, 256, 0, stream>>>(uemb, iemb, dinv, A);

  const int sgrid = (NROWS * 64) / 256;  // one wave per row
  spmm_kernel<<<sgrid, 256, 0, stream>>>(rowp, ccol, dinv2, A, B);  // Z1
  spmm_kernel<<<sgrid, 256, 0, stream>>>(rowp, ccol, dinv2, B, A);  // Z2

  // layer-3 only at sampled rows: 49152 waves
  gather3_kernel<<<(3 * BATCH * 64) / 256, 256, 0, stream>>>(
      u, ii, jj, rowp, ccol, dinv, A, E);

  // light loss: one wave per sample, direct loads only
  loss_kernel<<<(BATCH * 64) / 256, 256, 0, stream>>>(
      u, ii, jj, uemb, iemb, B, A, E, rsq, scal);
  finalize_kernel<<<1, 1, 0, stream>>>(scal, out);
}

// Round 13
// 490.410 us; speedup vs baseline: 1.8273x; 1.8273x over previous
//
#include <hip/hip_runtime.h>

#define NUM_USER 100000
#define NUM_ITEM 50000
#define HID 64
#define NNZ 1600000
#define NEDGE (2 * NNZ)          // 3,200,000
#define REGC 1e-4f
#define BATCH 16384
#define NROWS (NUM_USER + NUM_ITEM)   // 150,000
#define NELEM (NROWS * HID)           // 9,600,000

#define NB 1024                  // edge-slice blocks
#define SLICE (NEDGE / NB)       // 3125 exact
#define RPP 512                  // rows per coarse partition (row >> 9)
#define NPART ((NROWS + RPP - 1) / RPP)  // 293
#define NBLK_LOSS (BATCH / 4)    // 4096 loss blocks (4 waves each)

// ---------------------------------------------------------------------------
// passA: per-block LDS histogram of coarse partition ids -> cmat[p][b]
// ---------------------------------------------------------------------------
__global__ __launch_bounds__(256) void passA_kernel(const int* __restrict__ erow,
                                                    int* __restrict__ cmat) {
  __shared__ int h[NPART];
  const int b = blockIdx.x, t = threadIdx.x;
  if (t < NPART) h[t] = 0;
  if (t + 256 < NPART) h[t + 256] = 0;
  __syncthreads();
  const int s = b * SLICE, e = s + SLICE;
  for (int i = s + t; i < e; i += 256) atomicAdd(&h[erow[i] >> 9], 1);
  __syncthreads();
  if (t < NPART) cmat[t * NB + b] = h[t];
  if (t + 256 < NPART) cmat[(t + 256) * NB + b] = h[t + 256];
}

// ---------------------------------------------------------------------------
// scan_bp: per-partition exclusive scan over blocks, in place; totals out.
// ---------------------------------------------------------------------------
__global__ __launch_bounds__(64) void scan_bp_kernel(int* __restrict__ cmat,
                                                     int* __restrict__ totals) {
  const int p = blockIdx.x;
  const int lane = threadIdx.x;
  int* col = cmat + (size_t)p * NB;
  int carry = 0;
  for (int base = 0; base < NB; base += 64) {
    const int v = col[base + lane];
    int incl = v;
    for (int off = 1; off < 64; off <<= 1) {
      const int tt = __shfl_up(incl, off);
      if (lane >= off) incl += tt;
    }
    col[base + lane] = carry + incl - v;  // exclusive within partition
    carry += __shfl(incl, 63);
  }
  if (lane == 0) totals[p] = carry;
}

// ---------------------------------------------------------------------------
// scan_base: exclusive scan of partition totals -> pbase; misc zeroing
// ---------------------------------------------------------------------------
__global__ __launch_bounds__(512) void scan_base_kernel(
    const int* __restrict__ totals, int* __restrict__ pbase,
    int* __restrict__ rowp) {
  __shared__ int sA[512], sB[512];
  const int t = threadIdx.x;
  const int v = (t < NPART) ? totals[t] : 0;
  sA[t] = v;
  __syncthreads();
  int* in = sA;
  int* out = sB;
  for (int off = 1; off < 512; off <<= 1) {
    out[t] = in[t] + ((t >= off) ? in[t - off] : 0);
    __syncthreads();
    int* tmp = in; in = out; out = tmp;
  }
  if (t < NPART) pbase[t] = in[t] - v;
  if (t == 0) {
    pbase[NPART] = NEDGE;
    rowp[NROWS] = NEDGE;
  }
}

// ---------------------------------------------------------------------------
// passC: scatter edges into partition buckets; no global atomics.
// bucket word: (row & 511) << 18 | col   (col < 150000 < 2^18)
// ---------------------------------------------------------------------------
__global__ __launch_bounds__(256) void passC_kernel(
    const int* __restrict__ erow, const int* __restrict__ ecol,
    const int* __restrict__ cmat, const int* __restrict__ pbase,
    unsigned int* __restrict__ bucket) {
  __shared__ int cur[NPART];
  const int b = blockIdx.x, t = threadIdx.x;
  if (t < NPART) cur[t] = pbase[t] + cmat[t * NB + b];
  if (t + 256 < NPART) cur[t + 256] = pbase[t + 256] + cmat[(t + 256) * NB + b];
  __syncthreads();
  const int s = b * SLICE, e = s + SLICE;
  for (int i = s + t; i < e; i += 256) {
    const int r = erow[i];
    const int c = ecol[i];
    const int pos = atomicAdd(&cur[r >> 9], 1);
    bucket[pos] = ((unsigned int)(r & (RPP - 1)) << 18) | (unsigned int)c;
  }
}

// ---------------------------------------------------------------------------
// fine: one block per partition -> rowp/dinv/dinv2/rsq + final CSR ccol.
// ---------------------------------------------------------------------------
__global__ __launch_bounds__(256) void fine_kernel(
    const unsigned int* __restrict__ bucket, const int* __restrict__ pbase,
    int* __restrict__ ccol, int* __restrict__ rowp, float* __restrict__ dinv,
    float* __restrict__ dinv2, float* __restrict__ rsq) {
  __shared__ int cnt[RPP], sA[RPP], sB[RPP];
  const int p = blockIdx.x, t = threadIdx.x;
  const int start = pbase[p], end = pbase[p + 1];
  cnt[t] = 0;
  cnt[t + 256] = 0;
  __syncthreads();
  for (int i = start + t; i < end; i += 256) atomicAdd(&cnt[bucket[i] >> 18], 1);
  __syncthreads();
  sA[t] = cnt[t];
  sA[t + 256] = cnt[t + 256];
  __syncthreads();
  int* in = sA;
  int* out = sB;
  for (int off = 1; off < RPP; off <<= 1) {
    out[t] = in[t] + ((t >= off) ? in[t - off] : 0);
    const int t2 = t + 256;
    out[t2] = in[t2] + ((t2 >= off) ? in[t2 - off] : 0);
    __syncthreads();
    int* tmp = in; in = out; out = tmp;
  }
  // in[] = inclusive scan of cnt
  for (int r = t; r < RPP; r += 256) {
    const int row = p * RPP + r;
    if (row < NROWS) {
      const int deg = cnt[r];
      rowp[row] = start + in[r] - deg;
      dinv[row] = (deg > 0) ? (1.0f / sqrtf((float)deg)) : 0.f;
      dinv2[row] = (deg > 0) ? (1.0f / (float)deg) : 0.f;
      rsq[row] = (deg > 0) ? sqrtf((float)deg) : 0.f;
    }
  }
  out[t] = 0;
  out[t + 256] = 0;
  __syncthreads();
  for (int i = start + t; i < end; i += 256) {
    const unsigned int w = bucket[i];
    const int rl = w >> 18;
    const int posl = atomicAdd(&out[rl], 1);
    ccol[start + in[rl] - cnt[rl] + posl] = (int)(w & 0x3FFFFu);
  }
}

// ---------------------------------------------------------------------------
// init: Z0 = dinv ⊙ concat(uemb, iemb)
// ---------------------------------------------------------------------------
__global__ __launch_bounds__(256) void init_kernel(const float* __restrict__ uemb,
                                                   const float* __restrict__ iemb,
                                                   const float* __restrict__ dinv,
                                                   float* __restrict__ A) {
  const int tid = blockIdx.x * blockDim.x + threadIdx.x;
  const int stride = gridDim.x * blockDim.x;
  const int n4 = NELEM / 4;
  const int u4n = NUM_USER * HID / 4;
  const float4* __restrict__ u4 = (const float4*)uemb;
  const float4* __restrict__ i4 = (const float4*)iemb;
  float4* __restrict__ A4 = (float4*)A;
  for (int k = tid; k < n4; k += stride) {
    float4 v = (k < u4n) ? u4[k] : i4[k - u4n];
    const float dv = dinv[k >> 4];   // 16 float4 per row
    v.x *= dv; v.y *= dv; v.z *= dv; v.w *= dv;
    A4[k] = v;
  }
}

// ---------------------------------------------------------------------------
// shared gather helper: sum_{c in nbr(row)} z[c*64+lane]
// ---------------------------------------------------------------------------
__device__ __forceinline__ float row_gather_sum(
    const int* __restrict__ rowp, const int* __restrict__ ccol,
    const float* __restrict__ z, int row, int lane) {
  const int start = rowp[row];
  const int end = rowp[row + 1];
  float acc = 0.f;
  for (int base = start; base < end; base += 64) {
    const int idx = base + lane;
    const int cl = (idx < end) ? (ccol[idx] << 6) : 0;
    const int n = min(64, end - base);
    int k = 0;
    for (; k + 8 <= n; k += 8) {
      const int c0 = __shfl(cl, k + 0), c1 = __shfl(cl, k + 1);
      const int c2 = __shfl(cl, k + 2), c3 = __shfl(cl, k + 3);
      const int c4 = __shfl(cl, k + 4), c5 = __shfl(cl, k + 5);
      const int c6 = __shfl(cl, k + 6), c7 = __shfl(cl, k + 7);
      const float v0 = z[c0 + lane], v1 = z[c1 + lane];
      const float v2 = z[c2 + lane], v3 = z[c3 + lane];
      const float v4 = z[c4 + lane], v5 = z[c5 + lane];
      const float v6 = z[c6 + lane], v7 = z[c7 + lane];
      acc += v0; acc += v1; acc += v2; acc += v3;
      acc += v4; acc += v5; acc += v6; acc += v7;
    }
    for (; k < n; ++k) {
      const int c = __shfl(cl, k);
      acc += z[c + lane];
    }
  }
  return acc;
}

// ---------------------------------------------------------------------------
// spmm (pull, CSR): Z_out[r] = dinv2[r] * sum_{c in nbr(r)} Z_in[c]
// one wave per row, lane = hidden dim.
// ---------------------------------------------------------------------------
__global__ __launch_bounds__(256) void spmm_kernel(
    const int* __restrict__ rowp, const int* __restrict__ ccol,
    const float* __restrict__ dinv2, const float* __restrict__ zin,
    float* __restrict__ zout) {
  const int lane = threadIdx.x & 63;
  const int row = (blockIdx.x * blockDim.x + threadIdx.x) >> 6;
  if (row >= NROWS) return;
  const float yv = row_gather_sum(rowp, ccol, zin, row, lane);
  zout[(row << 6) + lane] = yv * dinv2[row];
}

// ---------------------------------------------------------------------------
// gather3: layer-3 ONLY at sampled rows. One wave per (sample,slot):
// slots [0,B) = u rows, [B,2B) = i rows, [2B,3B) = j rows.
// E[s] = dinv[row] * sum_{c in nbr(row)} Z2[c]   (== X3[row]).
// ---------------------------------------------------------------------------
__global__ __launch_bounds__(256) void gather3_kernel(
    const int* __restrict__ u, const int* __restrict__ ii,
    const int* __restrict__ jj, const int* __restrict__ rowp,
    const int* __restrict__ ccol, const float* __restrict__ dinv,
    const float* __restrict__ z2, float* __restrict__ E) {
  const int s = (blockIdx.x * blockDim.x + threadIdx.x) >> 6;
  const int lane = threadIdx.x & 63;
  if (s >= 3 * BATCH) return;
  int row;
  if (s < BATCH) row = u[s];
  else if (s < 2 * BATCH) row = NUM_USER + ii[s - BATCH];
  else row = NUM_USER + jj[s - 2 * BATCH];
  const float acc = row_gather_sum(rowp, ccol, z2, row, lane);
  E[(s << 6) + lane] = acc * dinv[row];
}

// ---------------------------------------------------------------------------
// loss: one wave per sample, direct loads only. NO GLOBAL ATOMICS:
// 4-wave LDS block reduction -> partials[block] (float2: bpr_sum, l2_sum).
// (round-12 counters: 32768 same-address atomicAdds serialized as HBM RMWs
//  = 419 of 896 us. WRITE_SIZE 1024KB = 32768 x 32B confirmed.)
// ---------------------------------------------------------------------------
__global__ __launch_bounds__(256) void loss_kernel(
    const int* __restrict__ u, const int* __restrict__ ii,
    const int* __restrict__ jj, const float* __restrict__ uemb,
    const float* __restrict__ iemb, const float* __restrict__ Z1,
    const float* __restrict__ Z2, const float* __restrict__ E,
    const float* __restrict__ rsq, float2* __restrict__ partials) {
  __shared__ float2 lds[4];
  const int b = (blockIdx.x * blockDim.x + threadIdx.x) >> 6;  // < BATCH by grid
  const int lane = threadIdx.x & 63;
  const int wid = threadIdx.x >> 6;

  const int ur = u[b];
  const int il = ii[b];
  const int jl = jj[b];
  const int pr = NUM_USER + il;
  const int nr = NUM_USER + jl;
  const int uo = (ur << 6) + lane;
  const int po = (pr << 6) + lane;
  const int no = (nr << 6) + lane;

  const float e0u = uemb[uo];
  const float e0p = iemb[(il << 6) + lane];
  const float e0n = iemb[(jl << 6) + lane];
  const float z1u = Z1[uo], z2u = Z2[uo];
  const float z1p = Z1[po], z2p = Z2[po];
  const float z1n = Z1[no], z2n = Z2[no];
  const float Eu = E[(b << 6) + lane];
  const float Ep = E[((BATCH + b) << 6) + lane];
  const float En = E[((2 * BATCH + b) << 6) + lane];
  const float rqu = rsq[ur], rqp = rsq[pr], rqn = rsq[nr];

  const float ue = 0.25f * (e0u + (z1u + z2u) * rqu + Eu);
  const float pe = 0.25f * (e0p + (z1p + z2p) * rqp + Ep);
  const float ne = 0.25f * (e0n + (z1n + z2n) * rqn + En);

  float s1 = ue * pe;
  float s2 = ue * ne;
  float s3 = ue * ue + pe * pe + ne * ne;
  for (int off = 32; off; off >>= 1) {
    s1 += __shfl_down(s1, off);
    s2 += __shfl_down(s2, off);
    s3 += __shfl_down(s3, off);
  }
  if (lane == 0) {
    const float z = s1 - s2;
    const float ls = fminf(z, 0.f) - log1pf(expf(-fabsf(z)));
    lds[wid] = make_float2(ls, s3);
  }
  __syncthreads();
  if (threadIdx.x == 0) {
    const float2 a = lds[0], bb = lds[1], c = lds[2], d = lds[3];
    partials[blockIdx.x] =
        make_float2(a.x + bb.x + c.x + d.x, a.y + bb.y + c.y + d.y);
  }
}

// ---------------------------------------------------------------------------
// finalize: single block reduces NBLK_LOSS partial pairs -> scalar loss.
// ---------------------------------------------------------------------------
__global__ __launch_bounds__(1024) void finalize_kernel(
    const float2* __restrict__ partials, float* __restrict__ out) {
  __shared__ float sb[16], sl[16];
  const int t = threadIdx.x;
  float accb = 0.f, accl = 0.f;
  for (int i = t; i < NBLK_LOSS; i += 1024) {
    const float2 p = partials[i];
    accb += p.x;
    accl += p.y;
  }
  for (int off = 32; off; off >>= 1) {
    accb += __shfl_down(accb, off);
    accl += __shfl_down(accl, off);
  }
  const int wid = t >> 6, lane = t & 63;
  if (lane == 0) {
    sb[wid] = accb;
    sl[wid] = accl;
  }
  __syncthreads();
  if (t == 0) {
    float tb = 0.f, tl = 0.f;
    for (int w = 0; w < 16; ++w) {
      tb += sb[w];
      tl += sl[w];
    }
    const float bpr = -tb / (float)BATCH;
    const float l2 = tl * 0.5f / (float)BATCH;
    out[0] = bpr + REGC * l2;
  }
}

// ---------------------------------------------------------------------------
extern "C" void kernel_launch(void* const* d_in, const int* in_sizes, int n_in,
                              void* d_out, int out_size, void* d_ws,
                              size_t ws_size, hipStream_t stream) {
  const int* u = (const int*)d_in[0];
  const int* ii = (const int*)d_in[1];
  const int* jj = (const int*)d_in[2];
  const int* erow = (const int*)d_in[3];
  const int* ecol = (const int*)d_in[4];
  // d_in[5] (edge_val) unused: weights recomputed from degrees.
  const float* uemb = (const float*)d_in[6];
  const float* iemb = (const float*)d_in[7];
  float* out = (float*)d_out;

  float* ws = (float*)d_ws;
  float* A = ws;                       // Z0 -> Z2; hosts bucket+cmat first
  float* B = A + (size_t)NELEM;        // Z1
  int* ccol = (int*)(B + (size_t)NELEM);
  int* rowp = ccol + (size_t)NEDGE;    // NROWS+1
  float* dinv = (float*)(rowp + NROWS + 1);
  float* dinv2 = dinv + NROWS;
  float* rsq = dinv2 + NROWS;
  int* totals = (int*)(rsq + NROWS);   // NPART
  int* pbase = totals + NPART;         // NPART+1
  float* E = (float*)(pbase + NPART + 1);   // 3*BATCH*64 floats = 12.6 MB
  float2* partials = (float2*)(E + (size_t)3 * BATCH * HID);  // 4096 float2

  // aliased inside A (dead before init writes Z0):
  unsigned int* bucket = (unsigned int*)A;          // NEDGE u32 = 12.8 MB
  int* cmat = (int*)A + (size_t)NEDGE;              // NPART*NB ints = 1.2 MB

  passA_kernel<<<NB, 256, 0, stream>>>(erow, cmat);
  scan_bp_kernel<<<NPART, 64, 0, stream>>>(cmat, totals);
  scan_base_kernel<<<1, 512, 0, stream>>>(totals, pbase, rowp);
  passC_kernel<<<NB, 256, 0, stream>>>(erow, ecol, cmat, pbase, bucket);
  fine_kernel<<<NPART, 256, 0, stream>>>(bucket, pbase, ccol, rowp, dinv,
                                         dinv2, rsq);

  init_kernel<<<2048, 256, 0, stream>>>(uemb, iemb, dinv, A);

  const int sgrid = (NROWS * 64) / 256;  // one wave per row
  spmm_kernel<<<sgrid, 256, 0, stream>>>(rowp, ccol, dinv2, A, B);  // Z1
  spmm_kernel<<<sgrid, 256, 0, stream>>>(rowp, ccol, dinv2, B, A);  // Z2

  // layer-3 only at sampled rows: 49152 waves
  gather3_kernel<<<(3 * BATCH * 64) / 256, 256, 0, stream>>>(
      u, ii, jj, rowp, ccol, dinv, A, E);

  // loss: one wave per sample, block-reduced partials (no atomics)
  loss_kernel<<<NBLK_LOSS, 256, 0, stream>>>(u, ii, jj, uemb, iemb, B, A, E,
                                             rsq, partials);
  finalize_kernel<<<1, 1024, 0, stream>>>(partials, out);
}